// Round 1
// baseline (119.028 us; speedup 1.0000x reference)
//
#include <hip/hip_runtime.h>
#include <hip/hip_bf16.h>

typedef unsigned short u16;
typedef __attribute__((ext_vector_type(8))) __bf16 bf16x8;
typedef __attribute__((ext_vector_type(4))) float f32x4;

#define B_SZ 4096
#define D_SZ 1024
#define MARGIN 0.2f

__device__ __forceinline__ float bf2f(u16 u) {
  union { unsigned int i; float f; } v; v.i = ((unsigned int)u) << 16; return v.f;
}
__device__ __forceinline__ u16 f2bf(float x) {
  __hip_bfloat16 h = __float2bfloat16(x);
  u16 r; __builtin_memcpy(&r, &h, 2); return r;
}

// ---------------- normalize + cast to bf16 ----------------
// grid: (4096 rows, 2 matrices), block: 256. Each thread: 4 consecutive f32.
__global__ void norm_cast_kernel(const float* __restrict__ im,
                                 const float* __restrict__ tx,
                                 u16* __restrict__ imn,
                                 u16* __restrict__ txn) {
  const int row = blockIdx.x;
  const float* src = (blockIdx.y == 0 ? im : tx) + (size_t)row * D_SZ;
  u16* dst = (blockIdx.y == 0 ? imn : txn) + (size_t)row * D_SZ;
  const int t = threadIdx.x;
  float4 v = reinterpret_cast<const float4*>(src)[t];
  float ss = v.x * v.x + v.y * v.y + v.z * v.z + v.w * v.w;
#pragma unroll
  for (int off = 32; off > 0; off >>= 1) ss += __shfl_down(ss, off, 64);
  __shared__ float wss[4];
  if ((t & 63) == 0) wss[t >> 6] = ss;
  __syncthreads();
  float tot = (wss[0] + wss[1]) + (wss[2] + wss[3]);
  float scale = 1.0f / fmaxf(sqrtf(tot), 1e-12f);
  u16 o[4] = { f2bf(v.x * scale), f2bf(v.y * scale),
               f2bf(v.z * scale), f2bf(v.w * scale) };
  ushort4 pack; __builtin_memcpy(&pack, o, 8);
  reinterpret_cast<ushort4*>(dst)[t] = pack;
}

// ---------------- diag_i = dot(imn_i, txn_i) ----------------
// grid: 1024 blocks x 256 threads; one wave per row.
__global__ void diag_kernel(const u16* __restrict__ imn,
                            const u16* __restrict__ txn,
                            float* __restrict__ diag) {
  const int lane = threadIdx.x & 63;
  const int r = blockIdx.x * 4 + (threadIdx.x >> 6);
  const size_t base = (size_t)r * D_SZ + lane * 16;
  bf16x8 av0 = *(const bf16x8*)(imn + base);
  bf16x8 av1 = *(const bf16x8*)(imn + base + 8);
  bf16x8 bv0 = *(const bf16x8*)(txn + base);
  bf16x8 bv1 = *(const bf16x8*)(txn + base + 8);
  float s = 0.f;
#pragma unroll
  for (int i = 0; i < 8; i++) {
    s += (float)av0[i] * (float)bv0[i];
    s += (float)av1[i] * (float)bv1[i];
  }
#pragma unroll
  for (int off = 32; off > 0; off >>= 1) s += __shfl_down(s, off, 64);
  if (lane == 0) diag[r] = s;
}

// ---------------- GEMM (sim = imn @ txn^T) + fused hinge-loss epilogue ------
// 128x128 tile, BK=32, 4 waves (2x2), 4x4 fragments of 16x16x32 bf16 MFMA.
__device__ __forceinline__ void gload_lds16(const u16* g, u16* l) {
  __builtin_amdgcn_global_load_lds((__attribute__((address_space(1))) void*)g,
                                   (__attribute__((address_space(3))) void*)l,
                                   16, 0, 0);
}

__global__ __launch_bounds__(256) void gemm_loss_kernel(
    const u16* __restrict__ A,   // imn [4096][1024]
    const u16* __restrict__ Bt,  // txn [4096][1024]
    const float* __restrict__ diag,
    float* __restrict__ sim,     // d_out+1, row-major [4096][4096]
    float* __restrict__ loss) {
  __shared__ u16 As[128 * 32];
  __shared__ u16 Bs[128 * 32];
  const int tid = threadIdx.x;
  const int lane = tid & 63;
  const int wid = tid >> 6;
  const int tm = blockIdx.y * 128;
  const int tn = blockIdx.x * 128;
  const int wr = wid >> 1, wc = wid & 1;

  f32x4 acc[4][4] = {};

  // staging: each wave fills 32 rows of each tile via 2 global_load_lds (16B/lane)
  const int srow = lane >> 2;        // 0..15
  const int scol = (lane & 3) * 8;   // 0,8,16,24
  const u16* gA = A + (size_t)(tm + wid * 32 + srow) * D_SZ + scol;
  const u16* gB = Bt + (size_t)(tn + wid * 32 + srow) * D_SZ + scol;
  u16* lA = As + (wid * 32) * 32;    // wave-uniform LDS base
  u16* lB = Bs + (wid * 32) * 32;

  const int ar = lane & 15;
  const int ak = (lane >> 4) * 8;

  for (int k0 = 0; k0 < D_SZ; k0 += 32) {
    gload_lds16(gA + k0, lA);
    gload_lds16(gA + k0 + 16 * D_SZ, lA + 16 * 32);
    gload_lds16(gB + k0, lB);
    gload_lds16(gB + k0 + 16 * D_SZ, lB + 16 * 32);
    __syncthreads();
    bf16x8 a[4], b[4];
#pragma unroll
    for (int m = 0; m < 4; m++)
      a[m] = *(const bf16x8*)&As[(wr * 64 + m * 16 + ar) * 32 + ak];
#pragma unroll
    for (int n = 0; n < 4; n++)
      b[n] = *(const bf16x8*)&Bs[(wc * 64 + n * 16 + ar) * 32 + ak];
#pragma unroll
    for (int m = 0; m < 4; m++)
#pragma unroll
      for (int n = 0; n < 4; n++)
        acc[m][n] = __builtin_amdgcn_mfma_f32_16x16x32_bf16(a[m], b[n], acc[m][n], 0, 0, 0);
    __syncthreads();
  }

  // epilogue: write sim, accumulate hinge loss
  float dcs[4];
#pragma unroll
  for (int n = 0; n < 4; n++) dcs[n] = diag[tn + wc * 64 + n * 16 + ar];
  float lsum = 0.f;
#pragma unroll
  for (int m = 0; m < 4; m++) {
#pragma unroll
    for (int i = 0; i < 4; i++) {
      const int r = tm + wr * 64 + m * 16 + (lane >> 4) * 4 + i;
      const float dr = diag[r];
#pragma unroll
      for (int n = 0; n < 4; n++) {
        const int c = tn + wc * 64 + n * 16 + ar;
        const float s = acc[m][n][i];
        sim[(size_t)r * B_SZ + c] = s;
        if (r != c)
          lsum += fmaxf(MARGIN + s - dr, 0.f) + fmaxf(MARGIN + s - dcs[n], 0.f);
      }
    }
  }
#pragma unroll
  for (int off = 32; off > 0; off >>= 1) lsum += __shfl_down(lsum, off, 64);
  if (lane == 0) atomicAdd(loss, lsum);
}

extern "C" void kernel_launch(void* const* d_in, const int* in_sizes, int n_in,
                              void* d_out, int out_size, void* d_ws, size_t ws_size,
                              hipStream_t stream) {
  const float* im = (const float*)d_in[0];
  const float* tx = (const float*)d_in[1];
  float* out = (float*)d_out;
  float* loss = out;        // output 0: scalar total_loss
  float* sim = out + 1;     // output 1: [4096][4096]

  u16* imn = (u16*)d_ws;
  u16* txn = imn + (size_t)B_SZ * D_SZ;
  float* diag = (float*)(txn + (size_t)B_SZ * D_SZ);

  hipMemsetAsync(d_out, 0, sizeof(float), stream);
  norm_cast_kernel<<<dim3(B_SZ, 2), 256, 0, stream>>>(im, tx, imn, txn);
  diag_kernel<<<B_SZ / 4, 256, 0, stream>>>(imn, txn, diag);
  gemm_loss_kernel<<<dim3(B_SZ / 128, B_SZ / 128), 256, 0, stream>>>(imn, txn, diag, sim, loss);
}

// Round 2
// 114.306 us; speedup vs baseline: 1.0413x; 1.0413x over previous
//
#include <hip/hip_runtime.h>
#include <hip/hip_bf16.h>

typedef unsigned short u16;
typedef __attribute__((ext_vector_type(8))) __bf16 bf16x8;
typedef __attribute__((ext_vector_type(4))) float f32x4;

#define B_SZ 4096
#define D_SZ 1024
#define MARGIN 0.2f

__device__ __forceinline__ u16 f2bf(float x) {
  __hip_bfloat16 h = __float2bfloat16(x);
  u16 r; __builtin_memcpy(&r, &h, 2); return r;
}

// ---------------- normalize + cast to bf16 + diag ----------------
// One block per row: loads im row and tx row, computes both norms and the
// cross dot product; diag[r] = dot/(|im| |tx|) so no separate diag pass.
__global__ void norm_diag_kernel(const float* __restrict__ im,
                                 const float* __restrict__ tx,
                                 u16* __restrict__ imn,
                                 u16* __restrict__ txn,
                                 float* __restrict__ diag) {
  const int row = blockIdx.x;
  const int t = threadIdx.x;
  const size_t base = (size_t)row * D_SZ;
  float4 vi = reinterpret_cast<const float4*>(im + base)[t];
  float4 vt = reinterpret_cast<const float4*>(tx + base)[t];
  float ssi = vi.x * vi.x + vi.y * vi.y + vi.z * vi.z + vi.w * vi.w;
  float sst = vt.x * vt.x + vt.y * vt.y + vt.z * vt.z + vt.w * vt.w;
  float dot = vi.x * vt.x + vi.y * vt.y + vi.z * vt.z + vi.w * vt.w;
#pragma unroll
  for (int off = 32; off > 0; off >>= 1) {
    ssi += __shfl_down(ssi, off, 64);
    sst += __shfl_down(sst, off, 64);
    dot += __shfl_down(dot, off, 64);
  }
  __shared__ float w[3][4];
  if ((t & 63) == 0) { int wi = t >> 6; w[0][wi] = ssi; w[1][wi] = sst; w[2][wi] = dot; }
  __syncthreads();
  const float tssi = (w[0][0] + w[0][1]) + (w[0][2] + w[0][3]);
  const float tsst = (w[1][0] + w[1][1]) + (w[1][2] + w[1][3]);
  const float tdot = (w[2][0] + w[2][1]) + (w[2][2] + w[2][3]);
  const float si = 1.0f / fmaxf(sqrtf(tssi), 1e-12f);
  const float st = 1.0f / fmaxf(sqrtf(tsst), 1e-12f);
  u16 oi[4] = { f2bf(vi.x * si), f2bf(vi.y * si), f2bf(vi.z * si), f2bf(vi.w * si) };
  u16 ot[4] = { f2bf(vt.x * st), f2bf(vt.y * st), f2bf(vt.z * st), f2bf(vt.w * st) };
  ushort4 pi, pt; __builtin_memcpy(&pi, oi, 8); __builtin_memcpy(&pt, ot, 8);
  reinterpret_cast<ushort4*>(imn + base)[t] = pi;
  reinterpret_cast<ushort4*>(txn + base)[t] = pt;
  if (t == 0) diag[row] = tdot * si * st;
}

// ---------------- GEMM (sim = imn @ txn^T) + fused hinge-loss epilogue ------
// 128x128 tile, BK=32, 4 waves (2x2), 4x4 frags of 16x16x32 bf16 MFMA.
// Round-2 changes: (a) double-buffered LDS + prefetch-1 (single barrier per
// K-step, stage latency hides under MFMA phase); (b) XOR swizzle e^=(row&3)*8
// applied on BOTH the global staging source and the LDS read (involution ->
// identity on data, 8-way bank conflict -> 4-way); (c) XCD-aware block swizzle.
__device__ __forceinline__ void gload_lds16(const u16* g, u16* l) {
  __builtin_amdgcn_global_load_lds((__attribute__((address_space(1))) void*)g,
                                   (__attribute__((address_space(3))) void*)l,
                                   16, 0, 0);
}

__global__ __launch_bounds__(256) void gemm_loss_kernel(
    const u16* __restrict__ A,   // imn [4096][1024]
    const u16* __restrict__ Bt,  // txn [4096][1024]
    const float* __restrict__ diag,
    float* __restrict__ sim,     // d_out+1, row-major [4096][4096]
    float* __restrict__ loss) {
  __shared__ u16 As[2 * 128 * 32];
  __shared__ u16 Bs[2 * 128 * 32];
  const int tid = threadIdx.x;
  const int lane = tid & 63;
  const int wid = tid >> 6;

  // XCD-aware swizzle: 1024 blocks, 8 XCDs, 128 consecutive tiles per XCD.
  const int flat = blockIdx.y * gridDim.x + blockIdx.x;
  const int s = (flat & 7) * 128 + (flat >> 3);
  const int tm = (s >> 5) * 128;
  const int tn = (s & 31) * 128;

  const int wr = wid >> 1, wc = wid & 1;

  f32x4 acc[4][4] = {};

  // staging addresses (pre-swizzled global source, rule #21)
  const int srow = lane >> 2;                       // 0..15
  const int sblk = (lane & 3) ^ (srow & 3);         // swizzled 8-elem block
  const u16* gA = A + (size_t)(tm + wid * 32 + srow) * D_SZ + sblk * 8;
  const u16* gB = Bt + (size_t)(tn + wid * 32 + srow) * D_SZ + sblk * 8;
  u16* lA = As + wid * 32 * 32;                     // wave-uniform LDS base
  u16* lB = Bs + wid * 32 * 32;

  const int ar = lane & 15;
  const int kx = ((lane >> 4) * 8) ^ ((lane & 3) * 8);  // swizzled k-offset

#define STAGE(buf, k0)                                            \
  do {                                                            \
    gload_lds16(gA + (k0), lA + (buf) * 4096);                    \
    gload_lds16(gA + (k0) + 16 * D_SZ, lA + (buf) * 4096 + 512);  \
    gload_lds16(gB + (k0), lB + (buf) * 4096);                    \
    gload_lds16(gB + (k0) + 16 * D_SZ, lB + (buf) * 4096 + 512);  \
  } while (0)

  STAGE(0, 0);
  __syncthreads();

  for (int t = 0; t < 32; ++t) {
    const int cur = t & 1;
    bf16x8 a[4], b[4];
    const u16* Ab = As + cur * 4096;
    const u16* Bb = Bs + cur * 4096;
#pragma unroll
    for (int m = 0; m < 4; m++)
      a[m] = *(const bf16x8*)&Ab[(wr * 64 + m * 16 + ar) * 32 + kx];
#pragma unroll
    for (int n = 0; n < 4; n++)
      b[n] = *(const bf16x8*)&Bb[(wc * 64 + n * 16 + ar) * 32 + kx];
    if (t + 1 < 32) STAGE(cur ^ 1, (t + 1) * 32);
#pragma unroll
    for (int m = 0; m < 4; m++)
#pragma unroll
      for (int n = 0; n < 4; n++)
        acc[m][n] = __builtin_amdgcn_mfma_f32_16x16x32_bf16(a[m], b[n], acc[m][n], 0, 0, 0);
    __syncthreads();
  }
#undef STAGE

  // epilogue: write sim, accumulate hinge loss
  float dcs[4];
#pragma unroll
  for (int n = 0; n < 4; n++) dcs[n] = diag[tn + wc * 64 + n * 16 + ar];
  float lsum = 0.f;
#pragma unroll
  for (int m = 0; m < 4; m++) {
#pragma unroll
    for (int i = 0; i < 4; i++) {
      const int r = tm + wr * 64 + m * 16 + (lane >> 4) * 4 + i;
      const float dr = diag[r];
#pragma unroll
      for (int n = 0; n < 4; n++) {
        const int c = tn + wc * 64 + n * 16 + ar;
        const float s_ = acc[m][n][i];
        sim[(size_t)r * B_SZ + c] = s_;
        if (r != c)
          lsum += fmaxf(MARGIN + s_ - dr, 0.f) + fmaxf(MARGIN + s_ - dcs[n], 0.f);
      }
    }
  }
#pragma unroll
  for (int off = 32; off > 0; off >>= 1) lsum += __shfl_down(lsum, off, 64);
  if (lane == 0) atomicAdd(loss, lsum);
}

extern "C" void kernel_launch(void* const* d_in, const int* in_sizes, int n_in,
                              void* d_out, int out_size, void* d_ws, size_t ws_size,
                              hipStream_t stream) {
  const float* im = (const float*)d_in[0];
  const float* tx = (const float*)d_in[1];
  float* out = (float*)d_out;
  float* loss = out;        // output 0: scalar total_loss
  float* sim = out + 1;     // output 1: [4096][4096]

  u16* imn = (u16*)d_ws;
  u16* txn = imn + (size_t)B_SZ * D_SZ;
  float* diag = (float*)(txn + (size_t)B_SZ * D_SZ);

  hipMemsetAsync(d_out, 0, sizeof(float), stream);
  norm_diag_kernel<<<B_SZ, 256, 0, stream>>>(im, tx, imn, txn, diag);
  gemm_loss_kernel<<<dim3(B_SZ / 128, B_SZ / 128), 256, 0, stream>>>(imn, txn, diag, sim, loss);
}